// Round 2
// baseline (63.455 us; speedup 1.0000x reference)
//
#include <hip/hip_runtime.h>

// RBF activation: out = sum_i w[c,i] * exp(-(x - mu_i)^2 / (2 sigma^2))
// Shapes: x (8,64,256,256) f32, w (1,64,1,1,31) f32, mu (31,) f32, sigma scalar.
// sigma == kernel spacing d, so only a 9-wide window of kernels around x
// contributes above ~3e-6 (threshold is 1.77e-3). Memory-bound target ~41us.

static constexpr int KW  = 31;  // number of RBF kernels
static constexpr int WIN = 9;   // window width (radius 4 => omitted terms < 3e-6)
static constexpr int RAD = 4;

typedef float f32x4 __attribute__((ext_vector_type(4)));  // native vector for nontemporal builtin

__device__ __forceinline__ float rbf_one(float xe, const float* __restrict__ wrow,
                                         float mu0, float dmu, float inv_d, float c2) {
    const float z  = xe - mu0;
    float jf = rintf(z * inv_d) - (float)RAD;          // window start index (float)
    jf = fminf(fmaxf(jf, 0.0f), (float)(KW - WIN));    // clamp to [0, 22]  (v_med3)
    const int   s = (int)jf;
    const float y = z - jf * dmu;                      // x - mu_s
    float acc = 0.0f;
#pragma unroll
    for (int k = 0; k < WIN; ++k) {
        const float dd = y - (float)k * dmu;           // x - mu_{s+k}
        acc = fmaf(wrow[s + k], __builtin_amdgcn_exp2f(c2 * dd * dd), acc);
    }
    return acc;
}

__global__ __launch_bounds__(256) void rbf_act_kernel(
    const float* __restrict__ x, const float* __restrict__ w,
    const float* __restrict__ mu, const float* __restrict__ sigma,
    float* __restrict__ out, int n4, int ntot) {
    // Stage weights: 64 channels x 31 taps, padded to stride 32 for shift addressing.
    __shared__ float lw[64 * 32];
    for (int t = threadIdx.x; t < 64 * KW; t += 256) {
        const int ch = t / KW;
        const int i  = t - ch * KW;
        lw[(ch << 5) + i] = w[t];
    }
    __syncthreads();

    // Uniform scalars from the actual input buffers (no hard-coded constants).
    const float mu0   = mu[0];
    const float dmu   = (mu[KW - 1] - mu0) * (1.0f / (KW - 1));
    const float inv_d = 1.0f / dmu;
    const float sg    = sigma[0];
    const float c2    = -1.4426950408889634f / (2.0f * sg * sg);  // -log2(e)/(2*sig^2)

    const int stride = gridDim.x * blockDim.x;
    const int gid    = blockIdx.x * blockDim.x + threadIdx.x;

    for (int i4 = gid; i4 < n4; i4 += stride) {
        const f32x4 xv = reinterpret_cast<const f32x4*>(x)[i4];
        // H*W = 65536 elements = 16384 float4 per channel row -> all 4 elems same c.
        const int c = (i4 >> 14) & 63;
        const float* wrow = &lw[c << 5];

        f32x4 ov;
        ov.x = rbf_one(xv.x, wrow, mu0, dmu, inv_d, c2);
        ov.y = rbf_one(xv.y, wrow, mu0, dmu, inv_d, c2);
        ov.z = rbf_one(xv.z, wrow, mu0, dmu, inv_d, c2);
        ov.w = rbf_one(xv.w, wrow, mu0, dmu, inv_d, c2);

        // Nontemporal: keep stores from evicting x from Infinity Cache.
        __builtin_nontemporal_store(ov, reinterpret_cast<f32x4*>(out) + i4);
    }

    // Scalar tail in case ntot % 4 != 0 (not hit for this shape, kept for safety).
    for (int i = n4 * 4 + gid; i < ntot; i += stride) {
        const float xe = x[i];
        const int c = (i >> 16) & 63;
        out[i] = rbf_one(xe, &lw[c << 5], mu0, dmu, inv_d, c2);
    }
}

extern "C" void kernel_launch(void* const* d_in, const int* in_sizes, int n_in,
                              void* d_out, int out_size, void* d_ws, size_t ws_size,
                              hipStream_t stream) {
    const float* x  = (const float*)d_in[0];
    const float* w  = (const float*)d_in[1];
    const float* mu = (const float*)d_in[2];
    const float* sg = (const float*)d_in[3];
    float* out = (float*)d_out;

    const int n4 = out_size >> 2;
    int blocks = (n4 + 255) / 256;
    if (blocks > 2048) blocks = 2048;   // grid-stride the rest (G11)
    if (blocks < 1) blocks = 1;

    rbf_act_kernel<<<blocks, 256, 0, stream>>>(x, w, mu, sg, out, n4, out_size);
}

// Round 3
// 48.406 us; speedup vs baseline: 1.3109x; 1.3109x over previous
//
#include <hip/hip_runtime.h>

// RBF activation: out[n,c,h,w] = sum_i w[c,i] * exp(-(x - mu_i)^2 / (2 sigma^2))
// x (8,64,256,256) f32, w (1,64,1,1,31) f32, mu (31,) f32, sigma scalar (== tap spacing d).
// Only a 7-wide window of taps contributes above ~1.8e-4 (threshold 1.77e-3).
// Gaussian chain computed by geometric recurrence: 2 exps/element instead of 7.

static constexpr int KW  = 31;  // number of RBF taps
static constexpr int WIN = 7;   // window width (radius 3; omitted taps >= 3.5 sigma)
static constexpr int RAD = 3;

typedef float f32x4 __attribute__((ext_vector_type(4)));  // native vector for nontemporal builtin

// E_k = exp2(cd2*(n-k)^2), via E_{k+1} = E_k * r_k, r_{k+1} = r_k * g,
// r_0 = exp2(cd2*(1-2n)), g = exp2(2*cd2).  (cd2 = -log2(e)*d^2/(2 sigma^2) < 0)
__device__ __forceinline__ float rbf_one(float xe, const float* __restrict__ wrow,
                                         float mu0, float inv_d, float cd2, float g) {
    const float t = (xe - mu0) * inv_d;            // position in tap units
    float jf = rintf(t) - (float)RAD;              // window start
    jf = fminf(fmaxf(jf, 0.0f), (float)(KW - WIN)); // clamp to [0, 24]  (v_med3)
    const int s = (int)jf;
    float n = t - jf;                              // offset from tap s, in tap units
    // Clamp so r0 = exp2(cd2*(1-2n)) stays finite when the window clamp leaves
    // n huge (|x| far outside [vmin,vmax]); there E0 underflows to 0 == true value.
    n = fminf(fmaxf(n, -32.0f), 40.0f);
    float E = __builtin_amdgcn_exp2f(cd2 * n * n);
    float r = __builtin_amdgcn_exp2f(cd2 * fmaf(-2.0f, n, 1.0f));
    float acc = 0.0f;
#pragma unroll
    for (int k = 0; k < WIN; ++k) {
        acc = fmaf(wrow[s + k], E, acc);           // 1 ds_read + 1 fma
        E *= r;                                    // advance Gaussian
        r *= g;
    }
    return acc;
}

__global__ __launch_bounds__(256) void rbf_act_kernel(
    const float* __restrict__ x, const float* __restrict__ w,
    const float* __restrict__ mu, const float* __restrict__ sigma,
    float* __restrict__ out, int n4, int ntot) {
    // Stage weights: 64 channels x 31 taps, stride 32 for shift addressing.
    __shared__ float lw[64 * 32];
    for (int t = threadIdx.x; t < 64 * KW; t += 256) {
        const int ch = t / KW;
        const int i  = t - ch * KW;
        lw[(ch << 5) + i] = w[t];
    }
    __syncthreads();

    // Uniform scalars from the actual input buffers (no hard-coded constants).
    const float mu0   = mu[0];
    const float dmu   = (mu[KW - 1] - mu0) * (1.0f / (KW - 1));
    const float inv_d = 1.0f / dmu;
    const float sg    = sigma[0];
    // cd2 = -log2(e) * d^2 / (2 sigma^2)   (exp2-domain quadratic coefficient)
    const float cd2   = -1.4426950408889634f * dmu * dmu / (2.0f * sg * sg);
    const float g     = exp2f(2.0f * cd2);

    const int stride = gridDim.x * blockDim.x;
    const int gid    = blockIdx.x * blockDim.x + threadIdx.x;

    for (int i4 = gid; i4 < n4; i4 += stride) {
        const f32x4 xv = reinterpret_cast<const f32x4*>(x)[i4];
        // H*W = 65536 elements = 16384 float4 per channel row -> all 4 elems same c.
        const int c = (i4 >> 14) & 63;
        const float* wrow = &lw[c << 5];

        f32x4 ov;
        ov.x = rbf_one(xv.x, wrow, mu0, inv_d, cd2, g);
        ov.y = rbf_one(xv.y, wrow, mu0, inv_d, cd2, g);
        ov.z = rbf_one(xv.z, wrow, mu0, inv_d, cd2, g);
        ov.w = rbf_one(xv.w, wrow, mu0, inv_d, cd2, g);

        // Nontemporal: keep stores from evicting x from Infinity Cache.
        __builtin_nontemporal_store(ov, reinterpret_cast<f32x4*>(out) + i4);
    }

    // Scalar tail (not hit for this shape, kept for safety).
    for (int i = n4 * 4 + gid; i < ntot; i += stride) {
        const int c = (i >> 16) & 63;
        out[i] = rbf_one(x[i], &lw[c << 5], mu0, inv_d, cd2, g);
    }
}

extern "C" void kernel_launch(void* const* d_in, const int* in_sizes, int n_in,
                              void* d_out, int out_size, void* d_ws, size_t ws_size,
                              hipStream_t stream) {
    const float* x  = (const float*)d_in[0];
    const float* w  = (const float*)d_in[1];
    const float* mu = (const float*)d_in[2];
    const float* sg = (const float*)d_in[3];
    float* out = (float*)d_out;

    const int n4 = out_size >> 2;
    int blocks = (n4 + 255) / 256;
    if (blocks > 2048) blocks = 2048;   // grid-stride the rest (G11)
    if (blocks < 1) blocks = 1;

    rbf_act_kernel<<<blocks, 256, 0, stream>>>(x, w, mu, sg, out, n4, out_size);
}

// Round 4
// 44.947 us; speedup vs baseline: 1.4118x; 1.0770x over previous
//
#include <hip/hip_runtime.h>

// RBF activation: out[n,c,h,w] = sum_i w[c,i] * exp(-(x - mu_i)^2 / (2 sigma^2))
// x (8,64,256,256) f32, w (1,64,1,1,31) f32, mu (31,) f32, sigma scalar (== tap spacing).
//
// out = f_c(x) is a fixed smooth per-channel function -> per-block 1024-entry
// linear-interp LUT in LDS (entries are (value, delta) float2 pairs, so the
// per-element hot path is ~7 VALU + one aligned ds_read_b64 + fma).
// LUT interp error <= 18*h^2/8 ~ 1.6e-5 (threshold 1.77e-3).
// Block->channel mapping: grid=4096, stride per iteration = one full image,
// so each thread's channel is constant and block-uniform.

static constexpr int KW    = 31;    // number of RBF taps
static constexpr int WIN   = 9;     // build window (radius 4; truncation ~3e-6)
static constexpr int RAD   = 4;
static constexpr int LUT_N = 1024;  // LUT intervals

typedef float f32x4 __attribute__((ext_vector_type(4)));
typedef float f32x2 __attribute__((ext_vector_type(2)));

// Windowed Gaussian-sum via geometric recurrence (build path, runs ~4x/thread).
__device__ __forceinline__ float rbf_win(float xe, const float* __restrict__ wrow,
                                         float mu0, float inv_d, float cd2, float g) {
    const float t = (xe - mu0) * inv_d;             // position in tap units
    float jf = rintf(t) - (float)RAD;               // window start
    jf = fminf(fmaxf(jf, 0.0f), (float)(KW - WIN)); // clamp
    const int s = (int)jf;
    float n = t - jf;
    n = fminf(fmaxf(n, -32.0f), 40.0f);             // keep r0 finite far outside
    float E = __builtin_amdgcn_exp2f(cd2 * n * n);
    float r = __builtin_amdgcn_exp2f(cd2 * fmaf(-2.0f, n, 1.0f));
    float acc = 0.0f;
#pragma unroll
    for (int k = 0; k < WIN; ++k) {
        acc = fmaf(wrow[s + k], E, acc);
        E *= r;
        r *= g;
    }
    return acc;
}

__global__ __launch_bounds__(256) void rbf_lut_kernel(
    const float* __restrict__ x, const float* __restrict__ w,
    const float* __restrict__ mu, const float* __restrict__ sigma,
    float* __restrict__ out, int n4, int ntot, int iters) {
    __shared__ f32x2 lut2[LUT_N];
    __shared__ float wrow[32];

    const int tid = threadIdx.x;
    const int gs  = gridDim.x * blockDim.x;          // float4 stride per iteration
    const int gid = blockIdx.x * blockDim.x + tid;

    // Channel: H*W=65536 elems = 16384 float4 per row; 64 rows per image.
    // Per-iter stride gs*4 = one image -> c constant across iters, uniform per block.
    const int c = (gid >> 14) & 63;

    // Uniform scalars from the input buffers.
    const float mu0   = mu[0];
    const float muL   = mu[KW - 1];
    const float dmu   = (muL - mu0) * (1.0f / (KW - 1));
    const float inv_d = 1.0f / dmu;
    const float sg    = sigma[0];
    const float cd2   = -1.4426950408889634f * dmu * dmu / (2.0f * sg * sg); // tap-unit quad coeff
    const float g     = exp2f(2.0f * cd2);

    // LUT domain: [mu0 - pad, muL + pad], pad = 5.25 sigma (f there ~4e-8).
    const float pad  = 5.25f * sg;
    const float lo   = mu0 - pad;
    const float span = (muL - mu0) + 2.0f * pad;
    const float h    = span * (1.0f / (float)LUT_N);
    const float invh = (float)LUT_N / span;
    const float nlo  = -lo * invh;

    // Issue first x load before LUT build so HBM latency hides under the build.
    int i4 = gid;
    f32x4 xv = {};
    if (i4 < n4) xv = reinterpret_cast<const f32x4*>(x)[i4];

    // Stage this block's 31 weights.
    if (tid < KW) wrow[tid] = w[c * KW + tid];
    __syncthreads();

    // Build LUT: entry e = (f(node_e), f(node_{e+1}) - f(node_e)).
    for (int e = tid; e < LUT_N; e += 256) {
        const float xa = lo + (float)e * h;
        const float a  = rbf_win(xa,     wrow, mu0, inv_d, cd2, g);
        const float b  = rbf_win(xa + h, wrow, mu0, inv_d, cd2, g);
        f32x2 p; p.x = a; p.y = b - a;
        lut2[e] = p;
    }
    __syncthreads();

    const float tmax = (float)LUT_N - 0.001f;   // clamp so j <= LUT_N-1

    for (int k = 0; k < iters; ++k) {
        const int next = i4 + gs;
        f32x4 xn = xv;
        if (k + 1 < iters && next < n4) xn = reinterpret_cast<const f32x4*>(x)[next];

        if (i4 < n4) {
            f32x4 ov;
#pragma unroll
            for (int e = 0; e < 4; ++e) {
                float t = fmaf(xv[e], invh, nlo);
                t = fminf(fmaxf(t, 0.0f), tmax);  // v_med3
                const int j = (int)t;             // trunc == floor (t >= 0)
                const float frac = t - (float)j;
                const f32x2 ab = lut2[j];         // one ds_read_b64
                ov[e] = fmaf(frac, ab.y, ab.x);
            }
            __builtin_nontemporal_store(ov, reinterpret_cast<f32x4*>(out) + i4);
        }
        xv = xn;
        i4 = next;
    }

    // Scalar tail (<4 elems; not hit for this shape): exact 31-tap sum.
    const float cd2x = -1.4426950408889634f / (2.0f * sg * sg);
    for (int i = n4 * 4 + gid; i < ntot; i += gs) {
        const float xe = x[i];
        const int ct = (i >> 16) & 63;
        float acc = 0.0f;
        for (int q = 0; q < KW; ++q) {
            const float d = xe - (mu0 + (float)q * dmu);
            acc = fmaf(w[ct * KW + q], __builtin_amdgcn_exp2f(cd2x * d * d), acc);
        }
        out[i] = acc;
    }
}

extern "C" void kernel_launch(void* const* d_in, const int* in_sizes, int n_in,
                              void* d_out, int out_size, void* d_ws, size_t ws_size,
                              hipStream_t stream) {
    const float* x  = (const float*)d_in[0];
    const float* w  = (const float*)d_in[1];
    const float* mu = (const float*)d_in[2];
    const float* sg = (const float*)d_in[3];
    float* out = (float*)d_out;

    const int n4     = out_size >> 2;
    const int blocks = 4096;            // stride*4 == one image -> channel-stable
    const int gsz    = blocks * 256;
    const int iters  = (n4 + gsz - 1) / gsz;

    rbf_lut_kernel<<<blocks, 256, 0, stream>>>(x, w, mu, sg, out, n4, out_size, iters);
}